// Round 1
// baseline (295.585 us; speedup 1.0000x reference)
//
#include <hip/hip_runtime.h>
#include <stdint.h>
#include <math.h>

#define NTOK 8192
#define DIM  512
#define FDIM 2048
#define NEXP 8
#define RMAX 17408   // 136 * 128 >= 2*NTOK + NEXP*127 alignment pad
#define NMT  136
#define KSPLIT 2

typedef __attribute__((ext_vector_type(8))) __bf16 bf16x8;
typedef __attribute__((ext_vector_type(4))) float  f32x4;

// ---------------- gate / prep partition ----------------
#define GTPB 16                    // gate tokens per block (4 waves x 4 sequential)
#define GB_BLOCKS (NTOK / GTPB)    // 512 gate blocks, atomic-free
// 64x64 transpose tiles: W1 = (2048/64)x(512/64)x8 = 2048 tiles, W2 same
#define PREP_W1 (GB_BLOCKS)            // [512, 512+2048)
#define PREP_W2 (GB_BLOCKS + 2048)     // [2560, 4608)
#define PREP_TOTAL (GB_BLOCKS + 4096)

// ---------------- workspace layout (bytes) ----------------
#define OFF_W1T    ((size_t)0)
#define SZ_W1T     ((size_t)NEXP * DIM * FDIM * 2)   // 16.8 MB
#define OFF_W2T    (OFF_W1T + SZ_W1T)
#define SZ_W2T     SZ_W1T
#define OFF_H      (OFF_W2T + SZ_W2T)
#define SZ_H       ((size_t)RMAX * FDIM * 2)         // 71.3 MB
#define OFF_META   (OFF_H + SZ_H)                    // offsets[9] @0, mtile_e[136] @16
#define SZ_META    ((size_t)1024)
#define OFF_XG     (OFF_META + SZ_META)
#define SZ_XG      ((size_t)RMAX * DIM * 2)          // 17.8 MB; o1 (bf16 partial) aliases this
#define OFF_O1     OFF_XG                            // gemm2 runs after gemm1 -> xg dead
#define OFF_O0     (OFF_XG + SZ_XG)
#define SZ_O0      ((size_t)RMAX * DIM * 4)          // 35.7 MB fp32 partial
#define OFF_TOKE   (OFF_O0 + SZ_O0)
#define OFF_TOKLS  (OFF_TOKE + (size_t)NTOK * 8)
#define OFF_TOKG   (OFF_TOKLS + (size_t)NTOK * 8)
#define OFF_HISTP  (OFF_TOKG + (size_t)NTOK * 8)     // [512][8] int
#define OFF_BASEP  (OFF_HISTP + (size_t)GB_BLOCKS * NEXP * 4)
#define OFF_ROWS   (OFF_BASEP + (size_t)GB_BLOCKS * NEXP * 4)  // [NTOK] int2

__device__ __forceinline__ unsigned short f2bf(float f) {
  union { float f; unsigned int u; } v; v.f = f;
  unsigned int u = v.u;
  return (unsigned short)((u + 0x7fffu + ((u >> 16) & 1u)) >> 16);
}
__device__ __forceinline__ float bf2f(unsigned short u) {
  union { unsigned int u; float f; } v; v.u = ((unsigned int)u) << 16;
  return v.f;
}

// async 16B/lane global->LDS; lds base must be wave-uniform, HW adds lane*16
__device__ __forceinline__ void gld16(const unsigned short* g, unsigned short* l) {
  __builtin_amdgcn_global_load_lds(
      (const __attribute__((address_space(1))) void*)g,
      (__attribute__((address_space(3))) void*)l, 16, 0, 0);
}

// ---------------- fused prep: gate (front) | transpose W1 | transpose W2 ----------------
// 64x64 fp32->bf16 transpose tile, 256 threads, 16 elems/thread, padded LDS
__device__ __forceinline__ void transpose_tile64(const float* __restrict__ src,
                                                 unsigned short* __restrict__ dst,
                                                 int R, int C, int bx, int by, int bz) {
  __shared__ float t[64][65];
  const int r0 = by * 64, c0 = bx * 64;
  const float* s = src + (size_t)bz * R * C;
  unsigned short* d = dst + (size_t)bz * R * C;
  const int tr = threadIdx.x >> 6, tc = threadIdx.x & 63;  // tr 0..3
  #pragma unroll
  for (int i = 0; i < 16; i++)
    t[tr + i * 4][tc] = s[(size_t)(r0 + tr + i * 4) * C + (c0 + tc)];
  __syncthreads();
  #pragma unroll
  for (int i = 0; i < 16; i++)
    d[(size_t)(c0 + tr + i * 4) * R + (r0 + tc)] = f2bf(t[tc][tr + i * 4]);
}

// fp64 logits, top-2, softmax; per-block histogram written to hist_part (NO global atomics)
__device__ __forceinline__ void gate_body(int gb, const float* __restrict__ x,
                            const float* __restrict__ Wg,
                            int* __restrict__ hist_part, int2* __restrict__ tok_e,
                            int2* __restrict__ tok_ls, float2* __restrict__ tok_g) {
  __shared__ int hist[NEXP];
  __shared__ int le[GTPB][2];
  __shared__ int ls[GTPB][2];
  __shared__ float lg[GTPB][2];
  const int wid = threadIdx.x >> 6;
  const int lane = threadIdx.x & 63;
  if (threadIdx.x < NEXP) hist[threadIdx.x] = 0;
  __syncthreads();
  for (int t = 0; t < 4; t++) {
    const int lt = wid * 4 + t;
    const int n = gb * GTPB + lt;
    double acc[NEXP];
    #pragma unroll
    for (int e = 0; e < NEXP; e++) acc[e] = 0.0;
    #pragma unroll
    for (int i = 0; i < 8; i++) {
      int dd = lane + i * 64;
      double xv = (double)x[(size_t)n * DIM + dd];
      const float* wr = Wg + (size_t)dd * NEXP;
      #pragma unroll
      for (int e = 0; e < NEXP; e++) acc[e] += xv * (double)wr[e];
    }
    #pragma unroll
    for (int s = 32; s > 0; s >>= 1)
      #pragma unroll
      for (int e = 0; e < NEXP; e++) acc[e] += __shfl_xor(acc[e], s, 64);
    if (lane == 0) {
      int i0 = 0;
      #pragma unroll
      for (int e = 1; e < NEXP; e++) if (acc[e] > acc[i0]) i0 = e;
      int i1 = (i0 == 0) ? 1 : 0;
      #pragma unroll
      for (int e = 0; e < NEXP; e++) { if (e == i0 || e == i1) continue; if (acc[e] > acc[i1]) i1 = e; }
      double e1 = exp(acc[i1] - acc[i0]), ssum = 1.0 + e1;
      le[lt][0] = i0; le[lt][1] = i1;
      ls[lt][0] = atomicAdd(&hist[i0], 1);
      ls[lt][1] = atomicAdd(&hist[i1], 1);
      lg[lt][0] = (float)(1.0 / ssum); lg[lt][1] = (float)(e1 / ssum);
    }
  }
  __syncthreads();
  if (threadIdx.x < NEXP) hist_part[gb * NEXP + threadIdx.x] = hist[threadIdx.x];
  if (threadIdx.x < GTPB) {
    const int lt = threadIdx.x;
    const int n = gb * GTPB + lt;
    tok_e[n]  = make_int2(le[lt][0], le[lt][1]);
    tok_ls[n] = make_int2(ls[lt][0], ls[lt][1]);
    tok_g[n]  = make_float2(lg[lt][0], lg[lt][1]);
  }
}

__global__ __launch_bounds__(256) void prep_kernel(const float* __restrict__ W1,
    unsigned short* __restrict__ W1t, const float* __restrict__ W2,
    unsigned short* __restrict__ W2t, const float* __restrict__ x,
    const float* __restrict__ Wg, int* __restrict__ hist_part, int2* __restrict__ tok_e,
    int2* __restrict__ tok_ls, float2* __restrict__ tok_g) {
  const int b = blockIdx.x;
  if (b < GB_BLOCKS) {             // gate first: long-latency blocks overlap transposes
    gate_body(b, x, Wg, hist_part, tok_e, tok_ls, tok_g);
  } else if (b < PREP_W2) {        // W1: R=512, C=2048 -> 32 x 8 x 8 tiles of 64x64
    const int q = b - PREP_W1;
    transpose_tile64(W1, W1t, DIM, FDIM, q & 31, (q >> 5) & 7, q >> 8);
  } else {                         // W2: R=2048, C=512 -> 8 x 32 x 8 tiles of 64x64
    const int q = b - PREP_W2;
    transpose_tile64(W2, W2t, FDIM, DIM, q & 7, (q >> 3) & 31, q >> 8);
  }
}

// ---------------- scan: hist_part -> absolute base_part, offsets, mtile_e ----------------
__global__ __launch_bounds__(256) void scan_kernel(const int* __restrict__ hist_part,
    int* __restrict__ offsets, int* __restrict__ base_part, int* __restrict__ mtile_e) {
  __shared__ int hp[GB_BLOCKS * NEXP];   // 16 KB
  __shared__ int segsum[8][NEXP];
  __shared__ int segbase[8][NEXP];
  __shared__ int tot[NEXP];
  __shared__ int soff[NEXP + 1];
  for (int i = threadIdx.x; i < GB_BLOCKS * NEXP; i += 256) hp[i] = hist_part[i];
  __syncthreads();
  if (threadIdx.x < 64) {
    const int e = threadIdx.x & 7, s = threadIdx.x >> 3;   // 8 segments x 8 experts
    int run = 0;
    for (int b = s * 64; b < s * 64 + 64; b++) {
      int v = hp[b * NEXP + e]; hp[b * NEXP + e] = run; run += v;  // exclusive in-segment
    }
    segsum[s][e] = run;
  }
  __syncthreads();
  if (threadIdx.x < NEXP) {
    const int e = threadIdx.x;
    int run = 0;
    for (int s = 0; s < 8; s++) { segbase[s][e] = run; run += segsum[s][e]; }
    tot[e] = run;
  }
  __syncthreads();
  if (threadIdx.x == 0) {
    int off = 0;
    for (int e = 0; e < NEXP; e++) { soff[e] = off; offsets[e] = off; off += (tot[e] + 127) & ~127; }
    soff[NEXP] = off; offsets[NEXP] = off;
    for (int t = 0; t < NMT; t++) {
      int r = t * 128, e = NEXP - 1;
      for (int q = 0; q < NEXP; q++)
        if (r >= soff[q] && r < soff[q + 1]) { e = q; break; }
      mtile_e[t] = e;
    }
  }
  __syncthreads();
  for (int i = threadIdx.x; i < GB_BLOCKS * NEXP; i += 256) {
    const int b = i >> 3, e = i & 7;
    base_part[i] = soff[e] + segbase[b >> 6][e] + hp[i];
  }
}

// ---------------- gather: resolve rows, write xg (both slots), persist rows ----------------
__global__ void gather_kernel(const float* __restrict__ x, const int2* __restrict__ tok_e,
                              const int2* __restrict__ tok_ls, const int* __restrict__ base_part,
                              ushort4* __restrict__ xg, int2* __restrict__ rows) {
  const int n = blockIdx.x;
  int2 te = tok_e[n]; int2 tl = tok_ls[n];
  const int gb = n / GTPB;
  const int r0 = base_part[gb * NEXP + te.x] + tl.x;
  const int r1 = base_part[gb * NEXP + te.y] + tl.y;
  if (threadIdx.x == 0) rows[n] = make_int2(r0, r1);
  const float4* xr = (const float4*)(x + (size_t)n * DIM);
  float4 v = xr[threadIdx.x];
  ushort4 o;
  o.x = f2bf(v.x); o.y = f2bf(v.y); o.z = f2bf(v.z); o.w = f2bf(v.w);
  xg[(size_t)r0 * (DIM / 4) + threadIdx.x] = o;
  xg[(size_t)r1 * (DIM / 4) + threadIdx.x] = o;
}

// ---------------- 128x128xBK64 bf16 MFMA GEMM core ----------------
// T3 "minimum 2-phase": double-buffered LDS (64 KB), stage tile t+1 BEFORE
// computing tile t, single __syncthreads() per K-step (its implicit
// vmcnt(0)+lgkmcnt(0) drain lands after the MFMAs, so the global-load
// latency hides under compute instead of blocking all waves at a drain
// barrier). XOR chunk swizzle unchanged (slot [row][c] holds global chunk
// c^(row&7)); read side 2-way bank aliasing (free).
template <int K, int LDA, int LDB>
__device__ __forceinline__ void gemm_core(const unsigned short* __restrict__ A,
                                          const unsigned short* __restrict__ B,
                                          int m0, int n0, f32x4 acc[4][4]) {
  __shared__ __align__(16) unsigned short As[2][128 * 64];  // 2 x 16 KB
  __shared__ __align__(16) unsigned short Bs[2][128 * 64];  // 2 x 16 KB
  const int tid = threadIdx.x;
  const int wid = tid >> 6, lane = tid & 63;
  const int wm = (wid >> 1) * 64, wn = (wid & 1) * 64;
  const int quad = lane >> 4, l16 = lane & 15;
  const int srow = tid >> 3;                        // 0..31
  const int scol = ((tid & 7) ^ (srow & 7)) << 3;   // swizzled source chunk (elems)
  const int r7 = (l16 & 7) << 3;                    // read-side swizzle key (elems)
  const unsigned short* Ar = A + (size_t)(m0 + srow) * LDA + scol;
  const unsigned short* Br = B + (size_t)(n0 + srow) * LDB + scol;

  auto stage = [&](int c, int kt) {
    unsigned short* As_w = As[c] + 512 * wid;       // wave-uniform base
    unsigned short* Bs_w = Bs[c] + 512 * wid;
    #pragma unroll
    for (int p = 0; p < 4; p++) {
      gld16(Ar + (size_t)(32 * p) * LDA + kt, As_w + p * 2048);
      gld16(Br + (size_t)(32 * p) * LDB + kt, Bs_w + p * 2048);
    }
  };
  auto compute = [&](int c) {
    #pragma unroll
    for (int kk = 0; kk < 2; kk++) {
      const int swz = ((kk * 4 + quad) << 3) ^ r7;  // swizzled chunk offset (elems)
      bf16x8 af[4], bfr[4];
      #pragma unroll
      for (int i = 0; i < 4; i++) {
        af[i]  = *(const bf16x8*)(As[c] + (wm + i * 16 + l16) * 64 + swz);
        bfr[i] = *(const bf16x8*)(Bs[c] + (wn + i * 16 + l16) * 64 + swz);
      }
      #pragma unroll
      for (int mi = 0; mi < 4; mi++)
        #pragma unroll
        for (int ni = 0; ni < 4; ni++)
          acc[mi][ni] = __builtin_amdgcn_mfma_f32_16x16x32_bf16(af[mi], bfr[ni], acc[mi][ni], 0, 0, 0);
    }
  };

  stage(0, 0);
  __syncthreads();               // prologue drain: tile 0 resident
  int cur = 0;
  #pragma unroll 1
  for (int kt = 64; kt < K; kt += 64) {
    stage(cur ^ 1, kt);          // async issue next tile (other buffer)
    compute(cur);                // ds_read + 32 MFMA hide the load latency
    __syncthreads();             // drains vmcnt(0): next tile resident; all
                                 // waves done reading buf[cur] -> reusable
    cur ^= 1;
  }
  compute(cur);                  // epilogue tile, no barrier needed
}

// ---------------- GEMM1: h = relu(xg @ W1[e] + b1[e]) -> bf16 ----------------
__global__ __launch_bounds__(256, 2) void gemm1_kernel(const unsigned short* __restrict__ xg,
    const unsigned short* __restrict__ W1t, const int* __restrict__ mtile_e,
    const float* __restrict__ b1, unsigned short* __restrict__ h) {
  const int bm = blockIdx.x, bn = blockIdx.y;
  const int e = mtile_e[bm];
  f32x4 acc[4][4];
  #pragma unroll
  for (int i = 0; i < 4; i++)
    #pragma unroll
    for (int j = 0; j < 4; j++) acc[i][j] = (f32x4){0.f, 0.f, 0.f, 0.f};
  gemm_core<DIM, DIM, DIM>(xg, W1t + (size_t)e * FDIM * DIM, bm * 128, bn * 128, acc);
  const int tid = threadIdx.x, wid = tid >> 6, lane = tid & 63;
  const int wm = (wid >> 1) * 64, wn = (wid & 1) * 64, quad = lane >> 4, l16 = lane & 15;
  #pragma unroll
  for (int mi = 0; mi < 4; mi++) {
    #pragma unroll
    for (int ni = 0; ni < 4; ni++) {
      const int col = bn * 128 + wn + ni * 16 + l16;
      const float bb = b1[e * FDIM + col];
      #pragma unroll
      for (int r = 0; r < 4; r++) {
        const int row = bm * 128 + wm + mi * 16 + quad * 4 + r;
        float v = acc[mi][ni][r] + bb;
        h[(size_t)row * FDIM + col] = f2bf(v > 0.f ? v : 0.f);
      }
    }
  }
}

// ---------------- GEMM2 (split-K, deterministic): ks=0 -> o0 fp32, ks=1 -> o1 bf16 ----------------
__global__ __launch_bounds__(256, 2) void gemm2_kernel(const unsigned short* __restrict__ h,
    const unsigned short* __restrict__ W2t, const int* __restrict__ mtile_e,
    float* __restrict__ o0, unsigned short* __restrict__ o1) {
  const int bm = blockIdx.x, bn = blockIdx.y, ks = blockIdx.z;
  const int e = mtile_e[bm];
  const int k0 = ks * (FDIM / KSPLIT);
  f32x4 acc[4][4];
  #pragma unroll
  for (int i = 0; i < 4; i++)
    #pragma unroll
    for (int j = 0; j < 4; j++) acc[i][j] = (f32x4){0.f, 0.f, 0.f, 0.f};
  gemm_core<FDIM / KSPLIT, FDIM, FDIM>(h + k0, W2t + (size_t)e * DIM * FDIM + k0,
                                       bm * 128, bn * 128, acc);
  const int tid = threadIdx.x, wid = tid >> 6, lane = tid & 63;
  const int wm = (wid >> 1) * 64, wn = (wid & 1) * 64, quad = lane >> 4, l16 = lane & 15;
  if (ks == 0) {
    #pragma unroll
    for (int mi = 0; mi < 4; mi++)
      #pragma unroll
      for (int r = 0; r < 4; r++) {
        const int row = bm * 128 + wm + mi * 16 + quad * 4 + r;
        #pragma unroll
        for (int ni = 0; ni < 4; ni++) {
          const int col = bn * 128 + wn + ni * 16 + l16;
          o0[(size_t)row * DIM + col] = acc[mi][ni][r];
        }
      }
  } else {
    #pragma unroll
    for (int mi = 0; mi < 4; mi++)
      #pragma unroll
      for (int r = 0; r < 4; r++) {
        const int row = bm * 128 + wm + mi * 16 + quad * 4 + r;
        #pragma unroll
        for (int ni = 0; ni < 4; ni++) {
          const int col = bn * 128 + wn + ni * 16 + l16;
          o1[(size_t)row * DIM + col] = f2bf(acc[mi][ni][r]);
        }
      }
  }
}

// ---------------- combine: out[n] = log(g0*exp(o(r0)+b2[e0]) + g1*exp(o(r1)+b2[e1])) ----------------
__global__ void combine_kernel(const float* __restrict__ o0, const unsigned short* __restrict__ o1,
                               const int2* __restrict__ tok_e, const int2* __restrict__ rows,
                               const float2* __restrict__ tok_g, const float* __restrict__ b2,
                               float* __restrict__ out) {
  const int n = blockIdx.x;
  const int c = threadIdx.x * 4;  // 128 threads x float4
  int2 te = tok_e[n]; int2 rr = rows[n]; float2 tg = tok_g[n];
  const int r0 = rr.x, r1 = rr.y;
  float4 a0 = *(const float4*)(o0 + (size_t)r0 * DIM + c);
  float4 a1 = *(const float4*)(o0 + (size_t)r1 * DIM + c);
  ushort4 p0 = *(const ushort4*)(o1 + (size_t)r0 * DIM + c);
  ushort4 p1 = *(const ushort4*)(o1 + (size_t)r1 * DIM + c);
  float4 c0 = *(const float4*)(b2 + te.x * DIM + c);
  float4 c1 = *(const float4*)(b2 + te.y * DIM + c);
  float4 res;
  #pragma unroll
  for (int j = 0; j < 4; j++) {
    float v0 = ((const float*)&a0)[j] + bf2f(((const unsigned short*)&p0)[j]) + ((const float*)&c0)[j];
    float v1 = ((const float*)&a1)[j] + bf2f(((const unsigned short*)&p1)[j]) + ((const float*)&c1)[j];
    float v = tg.x * expf(v0) + tg.y * expf(v1);
    v = (v == 0.0f) ? 2.220446049250313e-16f : v;
    ((float*)&res)[j] = logf(v);
  }
  *(float4*)(out + (size_t)n * DIM + c) = res;
}

extern "C" void kernel_launch(void* const* d_in, const int* in_sizes, int n_in,
                              void* d_out, int out_size, void* d_ws, size_t ws_size,
                              hipStream_t stream) {
  const float* x  = (const float*)d_in[0];
  const float* Wg = (const float*)d_in[1];
  const float* W1 = (const float*)d_in[2];
  const float* b1 = (const float*)d_in[3];
  const float* W2 = (const float*)d_in[4];
  const float* b2 = (const float*)d_in[5];
  float* out = (float*)d_out;
  char* ws = (char*)d_ws;

  unsigned short* W1t = (unsigned short*)(ws + OFF_W1T);
  unsigned short* W2t = (unsigned short*)(ws + OFF_W2T);
  unsigned short* h   = (unsigned short*)(ws + OFF_H);
  int* meta    = (int*)(ws + OFF_META);
  int* offsets = meta;           // [9]
  int* mtile_e = meta + 16;      // [136]
  unsigned short* xg = (unsigned short*)(ws + OFF_XG);
  unsigned short* o1 = (unsigned short*)(ws + OFF_O1);  // aliases xg (dead after gemm1)
  float* o0      = (float*)(ws + OFF_O0);
  int2* tok_e    = (int2*)(ws + OFF_TOKE);
  int2* tok_ls   = (int2*)(ws + OFF_TOKLS);
  float2* tok_g  = (float2*)(ws + OFF_TOKG);
  int* hist_part = (int*)(ws + OFF_HISTP);
  int* base_part = (int*)(ws + OFF_BASEP);
  int2* rows     = (int2*)(ws + OFF_ROWS);

  prep_kernel<<<PREP_TOTAL, 256, 0, stream>>>(W1, W1t, W2, W2t, x, Wg,
                                              hist_part, tok_e, tok_ls, tok_g);
  scan_kernel<<<1, 256, 0, stream>>>(hist_part, offsets, base_part, mtile_e);
  gather_kernel<<<NTOK, 128, 0, stream>>>(x, tok_e, tok_ls, base_part, (ushort4*)xg, rows);
  gemm1_kernel<<<dim3(NMT, FDIM / 128), 256, 0, stream>>>(xg, W1t, mtile_e, b1, h);
  gemm2_kernel<<<dim3(NMT, DIM / 128, KSPLIT), 256, 0, stream>>>(h, W2t, mtile_e, o0, o1);
  combine_kernel<<<NTOK, 128, 0, stream>>>(o0, o1, tok_e, rows, tok_g, b2, out);
}

// Round 3
// 283.417 us; speedup vs baseline: 1.0429x; 1.0429x over previous
//
#include <hip/hip_runtime.h>
#include <stdint.h>
#include <math.h>

#define NTOK 8192
#define DIM  512
#define FDIM 2048
#define NEXP 8
#define RMAX 17408   // 136 * 128 >= 2*NTOK + NEXP*127 alignment pad
#define NMT  136
#define KSPLIT 2

typedef __attribute__((ext_vector_type(8))) __bf16 bf16x8;
typedef __attribute__((ext_vector_type(4))) float  f32x4;

// ---------------- gate / prep partition ----------------
#define GTPB 16                    // gate tokens per block (4 waves x 4 sequential)
#define GB_BLOCKS (NTOK / GTPB)    // 512 gate blocks, atomic-free
// 64x64 transpose tiles: W1 = (2048/64)x(512/64)x8 = 2048 tiles, W2 same
#define PREP_W1 (GB_BLOCKS)            // [512, 512+2048)
#define PREP_W2 (GB_BLOCKS + 2048)     // [2560, 4608)
#define PREP_TOTAL (GB_BLOCKS + 4096)

// ---------------- workspace layout (bytes) ----------------
#define OFF_W1T    ((size_t)0)
#define SZ_W1T     ((size_t)NEXP * DIM * FDIM * 2)   // 16.8 MB
#define OFF_W2T    (OFF_W1T + SZ_W1T)
#define SZ_W2T     SZ_W1T
#define OFF_H      (OFF_W2T + SZ_W2T)
#define SZ_H       ((size_t)RMAX * FDIM * 2)         // 71.3 MB
#define OFF_META   (OFF_H + SZ_H)                    // offsets[9] @0, mtile_e[136] @16
#define SZ_META    ((size_t)1024)
#define OFF_XG     (OFF_META + SZ_META)
#define SZ_XG      ((size_t)RMAX * DIM * 2)          // 17.8 MB; o1 (bf16 partial) aliases this
#define OFF_O1     OFF_XG                            // gemm2 runs after gemm1 -> xg dead
#define OFF_O0     (OFF_XG + SZ_XG)
#define SZ_O0      ((size_t)RMAX * DIM * 4)          // 35.7 MB fp32 partial
#define OFF_TOKE   (OFF_O0 + SZ_O0)
#define OFF_TOKLS  (OFF_TOKE + (size_t)NTOK * 8)
#define OFF_TOKG   (OFF_TOKLS + (size_t)NTOK * 8)
#define OFF_HISTP  (OFF_TOKG + (size_t)NTOK * 8)     // [512][8] int
#define OFF_BASEP  (OFF_HISTP + (size_t)GB_BLOCKS * NEXP * 4)
#define OFF_ROWS   (OFF_BASEP + (size_t)GB_BLOCKS * NEXP * 4)  // [NTOK] int2

__device__ __forceinline__ unsigned short f2bf(float f) {
  union { float f; unsigned int u; } v; v.f = f;
  unsigned int u = v.u;
  return (unsigned short)((u + 0x7fffu + ((u >> 16) & 1u)) >> 16);
}
__device__ __forceinline__ float bf2f(unsigned short u) {
  union { unsigned int u; float f; } v; v.u = ((unsigned int)u) << 16;
  return v.f;
}

// async 16B/lane global->LDS; lds base must be wave-uniform, HW adds lane*16
__device__ __forceinline__ void gld16(const unsigned short* g, unsigned short* l) {
  __builtin_amdgcn_global_load_lds(
      (const __attribute__((address_space(1))) void*)g,
      (__attribute__((address_space(3))) void*)l, 16, 0, 0);
}

// ---------------- fused prep: gate (front) | transpose W1 | transpose W2 ----------------
// 64x64 fp32->bf16 transpose tile, 256 threads, 16 elems/thread, padded LDS
__device__ __forceinline__ void transpose_tile64(const float* __restrict__ src,
                                                 unsigned short* __restrict__ dst,
                                                 int R, int C, int bx, int by, int bz) {
  __shared__ float t[64][65];
  const int r0 = by * 64, c0 = bx * 64;
  const float* s = src + (size_t)bz * R * C;
  unsigned short* d = dst + (size_t)bz * R * C;
  const int tr = threadIdx.x >> 6, tc = threadIdx.x & 63;  // tr 0..3
  #pragma unroll
  for (int i = 0; i < 16; i++)
    t[tr + i * 4][tc] = s[(size_t)(r0 + tr + i * 4) * C + (c0 + tc)];
  __syncthreads();
  #pragma unroll
  for (int i = 0; i < 16; i++)
    d[(size_t)(c0 + tr + i * 4) * R + (r0 + tc)] = f2bf(t[tc][tr + i * 4]);
}

// fp64 logits, top-2, softmax; per-block histogram written to hist_part (NO global atomics)
__device__ __forceinline__ void gate_body(int gb, const float* __restrict__ x,
                            const float* __restrict__ Wg,
                            int* __restrict__ hist_part, int2* __restrict__ tok_e,
                            int2* __restrict__ tok_ls, float2* __restrict__ tok_g) {
  __shared__ int hist[NEXP];
  __shared__ int le[GTPB][2];
  __shared__ int ls[GTPB][2];
  __shared__ float lg[GTPB][2];
  const int wid = threadIdx.x >> 6;
  const int lane = threadIdx.x & 63;
  if (threadIdx.x < NEXP) hist[threadIdx.x] = 0;
  __syncthreads();
  for (int t = 0; t < 4; t++) {
    const int lt = wid * 4 + t;
    const int n = gb * GTPB + lt;
    double acc[NEXP];
    #pragma unroll
    for (int e = 0; e < NEXP; e++) acc[e] = 0.0;
    #pragma unroll
    for (int i = 0; i < 8; i++) {
      int dd = lane + i * 64;
      double xv = (double)x[(size_t)n * DIM + dd];
      const float* wr = Wg + (size_t)dd * NEXP;
      #pragma unroll
      for (int e = 0; e < NEXP; e++) acc[e] += xv * (double)wr[e];
    }
    #pragma unroll
    for (int s = 32; s > 0; s >>= 1)
      #pragma unroll
      for (int e = 0; e < NEXP; e++) acc[e] += __shfl_xor(acc[e], s, 64);
    if (lane == 0) {
      int i0 = 0;
      #pragma unroll
      for (int e = 1; e < NEXP; e++) if (acc[e] > acc[i0]) i0 = e;
      int i1 = (i0 == 0) ? 1 : 0;
      #pragma unroll
      for (int e = 0; e < NEXP; e++) { if (e == i0 || e == i1) continue; if (acc[e] > acc[i1]) i1 = e; }
      double e1 = exp(acc[i1] - acc[i0]), ssum = 1.0 + e1;
      le[lt][0] = i0; le[lt][1] = i1;
      ls[lt][0] = atomicAdd(&hist[i0], 1);
      ls[lt][1] = atomicAdd(&hist[i1], 1);
      lg[lt][0] = (float)(1.0 / ssum); lg[lt][1] = (float)(e1 / ssum);
    }
  }
  __syncthreads();
  if (threadIdx.x < NEXP) hist_part[gb * NEXP + threadIdx.x] = hist[threadIdx.x];
  if (threadIdx.x < GTPB) {
    const int lt = threadIdx.x;
    const int n = gb * GTPB + lt;
    tok_e[n]  = make_int2(le[lt][0], le[lt][1]);
    tok_ls[n] = make_int2(ls[lt][0], ls[lt][1]);
    tok_g[n]  = make_float2(lg[lt][0], lg[lt][1]);
  }
}

__global__ __launch_bounds__(256) void prep_kernel(const float* __restrict__ W1,
    unsigned short* __restrict__ W1t, const float* __restrict__ W2,
    unsigned short* __restrict__ W2t, const float* __restrict__ x,
    const float* __restrict__ Wg, int* __restrict__ hist_part, int2* __restrict__ tok_e,
    int2* __restrict__ tok_ls, float2* __restrict__ tok_g) {
  const int b = blockIdx.x;
  if (b < GB_BLOCKS) {             // gate first: long-latency blocks overlap transposes
    gate_body(b, x, Wg, hist_part, tok_e, tok_ls, tok_g);
  } else if (b < PREP_W2) {        // W1: R=512, C=2048 -> 32 x 8 x 8 tiles of 64x64
    const int q = b - PREP_W1;
    transpose_tile64(W1, W1t, DIM, FDIM, q & 31, (q >> 5) & 7, q >> 8);
  } else {                         // W2: R=2048, C=512 -> 8 x 32 x 8 tiles of 64x64
    const int q = b - PREP_W2;
    transpose_tile64(W2, W2t, FDIM, DIM, q & 7, (q >> 3) & 31, q >> 8);
  }
}

// ---------------- scan: hist_part -> absolute base_part, offsets, mtile_e ----------------
__global__ __launch_bounds__(256) void scan_kernel(const int* __restrict__ hist_part,
    int* __restrict__ offsets, int* __restrict__ base_part, int* __restrict__ mtile_e) {
  __shared__ int hp[GB_BLOCKS * NEXP];   // 16 KB
  __shared__ int segsum[8][NEXP];
  __shared__ int segbase[8][NEXP];
  __shared__ int tot[NEXP];
  __shared__ int soff[NEXP + 1];
  for (int i = threadIdx.x; i < GB_BLOCKS * NEXP; i += 256) hp[i] = hist_part[i];
  __syncthreads();
  if (threadIdx.x < 64) {
    const int e = threadIdx.x & 7, s = threadIdx.x >> 3;   // 8 segments x 8 experts
    int run = 0;
    for (int b = s * 64; b < s * 64 + 64; b++) {
      int v = hp[b * NEXP + e]; hp[b * NEXP + e] = run; run += v;  // exclusive in-segment
    }
    segsum[s][e] = run;
  }
  __syncthreads();
  if (threadIdx.x < NEXP) {
    const int e = threadIdx.x;
    int run = 0;
    for (int s = 0; s < 8; s++) { segbase[s][e] = run; run += segsum[s][e]; }
    tot[e] = run;
  }
  __syncthreads();
  if (threadIdx.x == 0) {
    int off = 0;
    for (int e = 0; e < NEXP; e++) { soff[e] = off; offsets[e] = off; off += (tot[e] + 127) & ~127; }
    soff[NEXP] = off; offsets[NEXP] = off;
    for (int t = 0; t < NMT; t++) {
      int r = t * 128, e = NEXP - 1;
      for (int q = 0; q < NEXP; q++)
        if (r >= soff[q] && r < soff[q + 1]) { e = q; break; }
      mtile_e[t] = e;
    }
  }
  __syncthreads();
  for (int i = threadIdx.x; i < GB_BLOCKS * NEXP; i += 256) {
    const int b = i >> 3, e = i & 7;
    base_part[i] = soff[e] + segbase[b >> 6][e] + hp[i];
  }
}

// ---------------- gather: resolve rows, write xg (both slots), persist rows ----------------
__global__ void gather_kernel(const float* __restrict__ x, const int2* __restrict__ tok_e,
                              const int2* __restrict__ tok_ls, const int* __restrict__ base_part,
                              ushort4* __restrict__ xg, int2* __restrict__ rows) {
  const int n = blockIdx.x;
  int2 te = tok_e[n]; int2 tl = tok_ls[n];
  const int gb = n / GTPB;
  const int r0 = base_part[gb * NEXP + te.x] + tl.x;
  const int r1 = base_part[gb * NEXP + te.y] + tl.y;
  if (threadIdx.x == 0) rows[n] = make_int2(r0, r1);
  const float4* xr = (const float4*)(x + (size_t)n * DIM);
  float4 v = xr[threadIdx.x];
  ushort4 o;
  o.x = f2bf(v.x); o.y = f2bf(v.y); o.z = f2bf(v.z); o.w = f2bf(v.w);
  xg[(size_t)r0 * (DIM / 4) + threadIdx.x] = o;
  xg[(size_t)r1 * (DIM / 4) + threadIdx.x] = o;
}

// ---------------- 128x128xBK64 bf16 MFMA GEMM core ----------------
// Depth-2 counted-vmcnt pipeline (T3+T4): double-buffered LDS; buffer for
// K-step t is staged at the end of step t-2, so its 8 global_load_lds have
// ~2 full compute phases in flight before use. The wait is a COUNTED
// s_waitcnt vmcnt(8) (each wave owns exactly 8 loads/stage; the 8 newest
// stay in flight across the barrier) -- never drain-to-0 in the main loop.
// Raw s_barrier (no implicit vmcnt(0) drain, unlike __syncthreads).
// Correctness: each wave's ds_reads are consumed by MFMAs (compiler
// lgkmcnt) before it reaches the post-compute barrier, so re-staging
// buf[cur] after that barrier cannot race readers. sched_barrier(0) after
// each asm waitcnt pins ds_read/MFMA ordering (rule #18).
// T5: setprio(1) around the MFMA cluster (role-diverse waves now exist).
// XOR chunk swizzle unchanged: slot [row][c] holds global chunk c^(row&7).
template <int K, int LDA, int LDB>
__device__ __forceinline__ void gemm_core(const unsigned short* __restrict__ A,
                                          const unsigned short* __restrict__ B,
                                          int m0, int n0, f32x4 acc[4][4]) {
  __shared__ __align__(16) unsigned short As[2][128 * 64];  // 2 x 16 KB
  __shared__ __align__(16) unsigned short Bs[2][128 * 64];  // 2 x 16 KB
  const int tid = threadIdx.x;
  const int wid = tid >> 6, lane = tid & 63;
  const int wm = (wid >> 1) * 64, wn = (wid & 1) * 64;
  const int quad = lane >> 4, l16 = lane & 15;
  const int srow = tid >> 3;                        // 0..31
  const int scol = ((tid & 7) ^ (srow & 7)) << 3;   // swizzled source chunk (elems)
  const int r7 = (l16 & 7) << 3;                    // read-side swizzle key (elems)
  const unsigned short* Ar = A + (size_t)(m0 + srow) * LDA + scol;
  const unsigned short* Br = B + (size_t)(n0 + srow) * LDB + scol;

  auto stage = [&](int c, int kt) {
    unsigned short* As_w = As[c] + 512 * wid;       // wave-uniform base
    unsigned short* Bs_w = Bs[c] + 512 * wid;
    #pragma unroll
    for (int p = 0; p < 4; p++) {
      gld16(Ar + (size_t)(32 * p) * LDA + kt, As_w + p * 2048);
      gld16(Br + (size_t)(32 * p) * LDB + kt, Bs_w + p * 2048);
    }
  };
  auto compute = [&](int c) {
    __builtin_amdgcn_s_setprio(1);
    #pragma unroll
    for (int kk = 0; kk < 2; kk++) {
      const int swz = ((kk * 4 + quad) << 3) ^ r7;  // swizzled chunk offset (elems)
      bf16x8 af[4], bfr[4];
      #pragma unroll
      for (int i = 0; i < 4; i++) {
        af[i]  = *(const bf16x8*)(As[c] + (wm + i * 16 + l16) * 64 + swz);
        bfr[i] = *(const bf16x8*)(Bs[c] + (wn + i * 16 + l16) * 64 + swz);
      }
      #pragma unroll
      for (int mi = 0; mi < 4; mi++)
        #pragma unroll
        for (int ni = 0; ni < 4; ni++)
          acc[mi][ni] = __builtin_amdgcn_mfma_f32_16x16x32_bf16(af[mi], bfr[ni], acc[mi][ni], 0, 0, 0);
    }
    __builtin_amdgcn_s_setprio(0);
  };

  stage(0, 0);                   // K >= 192 always holds here (K = 512 or 1024)
  stage(1, 64);
  int cur = 0;
  #pragma unroll 1
  for (int kt = 0; kt < K - 128; kt += 64) {
    asm volatile("s_waitcnt vmcnt(8)" ::: "memory");  // oldest 8 (= buf[cur]) landed
    __builtin_amdgcn_s_barrier();                     // all waves: buf[cur] fully written
    __builtin_amdgcn_sched_barrier(0);
    compute(cur);
    __builtin_amdgcn_sched_barrier(0);
    __builtin_amdgcn_s_barrier();                     // all waves done reading buf[cur]
    stage(cur, kt + 128);                             // re-stage 2 steps ahead
    cur ^= 1;
  }
  // penultimate step: 16 outstanding, no further staging
  asm volatile("s_waitcnt vmcnt(8)" ::: "memory");
  __builtin_amdgcn_s_barrier();
  __builtin_amdgcn_sched_barrier(0);
  compute(cur);
  __builtin_amdgcn_sched_barrier(0);
  __builtin_amdgcn_s_barrier();
  cur ^= 1;
  // last step: 8 outstanding -> full drain
  asm volatile("s_waitcnt vmcnt(0)" ::: "memory");
  __builtin_amdgcn_s_barrier();
  __builtin_amdgcn_sched_barrier(0);
  compute(cur);
}

// ---------------- GEMM1: h = relu(xg @ W1[e] + b1[e]) -> bf16 ----------------
__global__ __launch_bounds__(256, 2) void gemm1_kernel(const unsigned short* __restrict__ xg,
    const unsigned short* __restrict__ W1t, const int* __restrict__ mtile_e,
    const float* __restrict__ b1, unsigned short* __restrict__ h) {
  const int bm = blockIdx.x, bn = blockIdx.y;
  const int e = mtile_e[bm];
  f32x4 acc[4][4];
  #pragma unroll
  for (int i = 0; i < 4; i++)
    #pragma unroll
    for (int j = 0; j < 4; j++) acc[i][j] = (f32x4){0.f, 0.f, 0.f, 0.f};
  gemm_core<DIM, DIM, DIM>(xg, W1t + (size_t)e * FDIM * DIM, bm * 128, bn * 128, acc);
  const int tid = threadIdx.x, wid = tid >> 6, lane = tid & 63;
  const int wm = (wid >> 1) * 64, wn = (wid & 1) * 64, quad = lane >> 4, l16 = lane & 15;
  #pragma unroll
  for (int mi = 0; mi < 4; mi++) {
    #pragma unroll
    for (int ni = 0; ni < 4; ni++) {
      const int col = bn * 128 + wn + ni * 16 + l16;
      const float bb = b1[e * FDIM + col];
      #pragma unroll
      for (int r = 0; r < 4; r++) {
        const int row = bm * 128 + wm + mi * 16 + quad * 4 + r;
        float v = acc[mi][ni][r] + bb;
        h[(size_t)row * FDIM + col] = f2bf(v > 0.f ? v : 0.f);
      }
    }
  }
}

// ---------------- GEMM2 (split-K, deterministic): ks=0 -> o0 fp32, ks=1 -> o1 bf16 ----------------
__global__ __launch_bounds__(256, 2) void gemm2_kernel(const unsigned short* __restrict__ h,
    const unsigned short* __restrict__ W2t, const int* __restrict__ mtile_e,
    float* __restrict__ o0, unsigned short* __restrict__ o1) {
  const int bm = blockIdx.x, bn = blockIdx.y, ks = blockIdx.z;
  const int e = mtile_e[bm];
  const int k0 = ks * (FDIM / KSPLIT);
  f32x4 acc[4][4];
  #pragma unroll
  for (int i = 0; i < 4; i++)
    #pragma unroll
    for (int j = 0; j < 4; j++) acc[i][j] = (f32x4){0.f, 0.f, 0.f, 0.f};
  gemm_core<FDIM / KSPLIT, FDIM, FDIM>(h + k0, W2t + (size_t)e * DIM * FDIM + k0,
                                       bm * 128, bn * 128, acc);
  const int tid = threadIdx.x, wid = tid >> 6, lane = tid & 63;
  const int wm = (wid >> 1) * 64, wn = (wid & 1) * 64, quad = lane >> 4, l16 = lane & 15;
  if (ks == 0) {
    #pragma unroll
    for (int mi = 0; mi < 4; mi++)
      #pragma unroll
      for (int r = 0; r < 4; r++) {
        const int row = bm * 128 + wm + mi * 16 + quad * 4 + r;
        #pragma unroll
        for (int ni = 0; ni < 4; ni++) {
          const int col = bn * 128 + wn + ni * 16 + l16;
          o0[(size_t)row * DIM + col] = acc[mi][ni][r];
        }
      }
  } else {
    #pragma unroll
    for (int mi = 0; mi < 4; mi++)
      #pragma unroll
      for (int r = 0; r < 4; r++) {
        const int row = bm * 128 + wm + mi * 16 + quad * 4 + r;
        #pragma unroll
        for (int ni = 0; ni < 4; ni++) {
          const int col = bn * 128 + wn + ni * 16 + l16;
          o1[(size_t)row * DIM + col] = f2bf(acc[mi][ni][r]);
        }
      }
  }
}

// ---------------- combine: out[n] = log(g0*exp(o(r0)+b2[e0]) + g1*exp(o(r1)+b2[e1])) ----------------
__global__ void combine_kernel(const float* __restrict__ o0, const unsigned short* __restrict__ o1,
                               const int2* __restrict__ tok_e, const int2* __restrict__ rows,
                               const float2* __restrict__ tok_g, const float* __restrict__ b2,
                               float* __restrict__ out) {
  const int n = blockIdx.x;
  const int c = threadIdx.x * 4;  // 128 threads x float4
  int2 te = tok_e[n]; int2 rr = rows[n]; float2 tg = tok_g[n];
  const int r0 = rr.x, r1 = rr.y;
  float4 a0 = *(const float4*)(o0 + (size_t)r0 * DIM + c);
  float4 a1 = *(const float4*)(o0 + (size_t)r1 * DIM + c);
  ushort4 p0 = *(const ushort4*)(o1 + (size_t)r0 * DIM + c);
  ushort4 p1 = *(const ushort4*)(o1 + (size_t)r1 * DIM + c);
  float4 c0 = *(const float4*)(b2 + te.x * DIM + c);
  float4 c1 = *(const float4*)(b2 + te.y * DIM + c);
  float4 res;
  #pragma unroll
  for (int j = 0; j < 4; j++) {
    float v0 = ((const float*)&a0)[j] + bf2f(((const unsigned short*)&p0)[j]) + ((const float*)&c0)[j];
    float v1 = ((const float*)&a1)[j] + bf2f(((const unsigned short*)&p1)[j]) + ((const float*)&c1)[j];
    float v = tg.x * expf(v0) + tg.y * expf(v1);
    v = (v == 0.0f) ? 2.220446049250313e-16f : v;
    ((float*)&res)[j] = logf(v);
  }
  *(float4*)(out + (size_t)n * DIM + c) = res;
}

extern "C" void kernel_launch(void* const* d_in, const int* in_sizes, int n_in,
                              void* d_out, int out_size, void* d_ws, size_t ws_size,
                              hipStream_t stream) {
  const float* x  = (const float*)d_in[0];
  const float* Wg = (const float*)d_in[1];
  const float* W1 = (const float*)d_in[2];
  const float* b1 = (const float*)d_in[3];
  const float* W2 = (const float*)d_in[4];
  const float* b2 = (const float*)d_in[5];
  float* out = (float*)d_out;
  char* ws = (char*)d_ws;

  unsigned short* W1t = (unsigned short*)(ws + OFF_W1T);
  unsigned short* W2t = (unsigned short*)(ws + OFF_W2T);
  unsigned short* h   = (unsigned short*)(ws + OFF_H);
  int* meta    = (int*)(ws + OFF_META);
  int* offsets = meta;           // [9]
  int* mtile_e = meta + 16;      // [136]
  unsigned short* xg = (unsigned short*)(ws + OFF_XG);
  unsigned short* o1 = (unsigned short*)(ws + OFF_O1);  // aliases xg (dead after gemm1)
  float* o0      = (float*)(ws + OFF_O0);
  int2* tok_e    = (int2*)(ws + OFF_TOKE);
  int2* tok_ls   = (int2*)(ws + OFF_TOKLS);
  float2* tok_g  = (float2*)(ws + OFF_TOKG);
  int* hist_part = (int*)(ws + OFF_HISTP);
  int* base_part = (int*)(ws + OFF_BASEP);
  int2* rows     = (int2*)(ws + OFF_ROWS);

  prep_kernel<<<PREP_TOTAL, 256, 0, stream>>>(W1, W1t, W2, W2t, x, Wg,
                                              hist_part, tok_e, tok_ls, tok_g);
  scan_kernel<<<1, 256, 0, stream>>>(hist_part, offsets, base_part, mtile_e);
  gather_kernel<<<NTOK, 128, 0, stream>>>(x, tok_e, tok_ls, base_part, (ushort4*)xg, rows);
  gemm1_kernel<<<dim3(NMT, FDIM / 128), 256, 0, stream>>>(xg, W1t, mtile_e, b1, h);
  gemm2_kernel<<<dim3(NMT, DIM / 128, KSPLIT), 256, 0, stream>>>(h, W2t, mtile_e, o0, o1);
  combine_kernel<<<NTOK, 128, 0, stream>>>(o0, o1, tok_e, rows, tok_g, b2, out);
}

// Round 4
// 280.534 us; speedup vs baseline: 1.0537x; 1.0103x over previous
//
#include <hip/hip_runtime.h>
#include <stdint.h>
#include <math.h>

#define NTOK 8192
#define DIM  512
#define FDIM 2048
#define NEXP 8
#define RMAX 17408   // 136 * 128 >= 2*NTOK + NEXP*127 alignment pad
#define NMT  136
#define KSPLIT 2

typedef __attribute__((ext_vector_type(8))) __bf16 bf16x8;
typedef __attribute__((ext_vector_type(4))) float  f32x4;

// ---------------- gate / prep partition ----------------
#define GTPB 16                    // gate tokens per block (4 waves x 4 sequential)
#define GB_BLOCKS (NTOK / GTPB)    // 512 gate blocks, atomic-free
// 64x64 transpose tiles: W1 = (2048/64)x(512/64)x8 = 2048 tiles, W2 same
#define PREP_W1 (GB_BLOCKS)            // [512, 512+2048)
#define PREP_W2 (GB_BLOCKS + 2048)     // [2560, 4608)
#define PREP_TOTAL (GB_BLOCKS + 4096)

// ---------------- workspace layout (bytes) ----------------
#define OFF_W1T    ((size_t)0)
#define SZ_W1T     ((size_t)NEXP * DIM * FDIM * 2)   // 16.8 MB
#define OFF_W2T    (OFF_W1T + SZ_W1T)
#define SZ_W2T     SZ_W1T
#define OFF_H      (OFF_W2T + SZ_W2T)
#define SZ_H       ((size_t)RMAX * FDIM * 2)         // 71.3 MB
#define OFF_META   (OFF_H + SZ_H)                    // offsets[9] @0, mtile_e[136] @16
#define SZ_META    ((size_t)1024)
#define OFF_XG     (OFF_META + SZ_META)
#define SZ_XG      ((size_t)RMAX * DIM * 2)          // 17.8 MB; o1 (bf16 partial) aliases this
#define OFF_O1     OFF_XG                            // gemm2 runs after gemm1 -> xg dead
#define OFF_O0     (OFF_XG + SZ_XG)
#define SZ_O0      ((size_t)RMAX * DIM * 4)          // 35.7 MB fp32 partial
#define OFF_TOKE   (OFF_O0 + SZ_O0)
#define OFF_TOKLS  (OFF_TOKE + (size_t)NTOK * 8)
#define OFF_TOKG   (OFF_TOKLS + (size_t)NTOK * 8)
#define OFF_HISTP  (OFF_TOKG + (size_t)NTOK * 8)     // [512][8] int
#define OFF_BASEP  (OFF_HISTP + (size_t)GB_BLOCKS * NEXP * 4)
#define OFF_ROWS   (OFF_BASEP + (size_t)GB_BLOCKS * NEXP * 4)  // [NTOK] int2

__device__ __forceinline__ unsigned short f2bf(float f) {
  union { float f; unsigned int u; } v; v.f = f;
  unsigned int u = v.u;
  return (unsigned short)((u + 0x7fffu + ((u >> 16) & 1u)) >> 16);
}
__device__ __forceinline__ float bf2f(unsigned short u) {
  union { unsigned int u; float f; } v; v.u = ((unsigned int)u) << 16;
  return v.f;
}

// async 16B/lane global->LDS; lds base must be wave-uniform, HW adds lane*16
__device__ __forceinline__ void gld16(const unsigned short* g, unsigned short* l) {
  __builtin_amdgcn_global_load_lds(
      (const __attribute__((address_space(1))) void*)g,
      (__attribute__((address_space(3))) void*)l, 16, 0, 0);
}

// ---------------- fused prep: gate (front) | transpose W1 | transpose W2 ----------------
// 64x64 fp32->bf16 transpose tile, 256 threads, 16 elems/thread, padded LDS
__device__ __forceinline__ void transpose_tile64(const float* __restrict__ src,
                                                 unsigned short* __restrict__ dst,
                                                 int R, int C, int bx, int by, int bz) {
  __shared__ float t[64][65];
  const int r0 = by * 64, c0 = bx * 64;
  const float* s = src + (size_t)bz * R * C;
  unsigned short* d = dst + (size_t)bz * R * C;
  const int tr = threadIdx.x >> 6, tc = threadIdx.x & 63;  // tr 0..3
  #pragma unroll
  for (int i = 0; i < 16; i++)
    t[tr + i * 4][tc] = s[(size_t)(r0 + tr + i * 4) * C + (c0 + tc)];
  __syncthreads();
  #pragma unroll
  for (int i = 0; i < 16; i++)
    d[(size_t)(c0 + tr + i * 4) * R + (r0 + tc)] = f2bf(t[tc][tr + i * 4]);
}

// fp64 logits, top-2, softmax; per-block histogram written to hist_part (NO global atomics)
__device__ __forceinline__ void gate_body(int gb, const float* __restrict__ x,
                            const float* __restrict__ Wg,
                            int* __restrict__ hist_part, int2* __restrict__ tok_e,
                            int2* __restrict__ tok_ls, float2* __restrict__ tok_g) {
  __shared__ int hist[NEXP];
  __shared__ int le[GTPB][2];
  __shared__ int ls[GTPB][2];
  __shared__ float lg[GTPB][2];
  const int wid = threadIdx.x >> 6;
  const int lane = threadIdx.x & 63;
  if (threadIdx.x < NEXP) hist[threadIdx.x] = 0;
  __syncthreads();
  for (int t = 0; t < 4; t++) {
    const int lt = wid * 4 + t;
    const int n = gb * GTPB + lt;
    double acc[NEXP];
    #pragma unroll
    for (int e = 0; e < NEXP; e++) acc[e] = 0.0;
    #pragma unroll
    for (int i = 0; i < 8; i++) {
      int dd = lane + i * 64;
      double xv = (double)x[(size_t)n * DIM + dd];
      const float* wr = Wg + (size_t)dd * NEXP;
      #pragma unroll
      for (int e = 0; e < NEXP; e++) acc[e] += xv * (double)wr[e];
    }
    #pragma unroll
    for (int s = 32; s > 0; s >>= 1)
      #pragma unroll
      for (int e = 0; e < NEXP; e++) acc[e] += __shfl_xor(acc[e], s, 64);
    if (lane == 0) {
      int i0 = 0;
      #pragma unroll
      for (int e = 1; e < NEXP; e++) if (acc[e] > acc[i0]) i0 = e;
      int i1 = (i0 == 0) ? 1 : 0;
      #pragma unroll
      for (int e = 0; e < NEXP; e++) { if (e == i0 || e == i1) continue; if (acc[e] > acc[i1]) i1 = e; }
      double e1 = exp(acc[i1] - acc[i0]), ssum = 1.0 + e1;
      le[lt][0] = i0; le[lt][1] = i1;
      ls[lt][0] = atomicAdd(&hist[i0], 1);
      ls[lt][1] = atomicAdd(&hist[i1], 1);
      lg[lt][0] = (float)(1.0 / ssum); lg[lt][1] = (float)(e1 / ssum);
    }
  }
  __syncthreads();
  if (threadIdx.x < NEXP) hist_part[gb * NEXP + threadIdx.x] = hist[threadIdx.x];
  if (threadIdx.x < GTPB) {
    const int lt = threadIdx.x;
    const int n = gb * GTPB + lt;
    tok_e[n]  = make_int2(le[lt][0], le[lt][1]);
    tok_ls[n] = make_int2(ls[lt][0], ls[lt][1]);
    tok_g[n]  = make_float2(lg[lt][0], lg[lt][1]);
  }
}

__global__ __launch_bounds__(256) void prep_kernel(const float* __restrict__ W1,
    unsigned short* __restrict__ W1t, const float* __restrict__ W2,
    unsigned short* __restrict__ W2t, const float* __restrict__ x,
    const float* __restrict__ Wg, int* __restrict__ hist_part, int2* __restrict__ tok_e,
    int2* __restrict__ tok_ls, float2* __restrict__ tok_g) {
  const int b = blockIdx.x;
  if (b < GB_BLOCKS) {             // gate first: long-latency blocks overlap transposes
    gate_body(b, x, Wg, hist_part, tok_e, tok_ls, tok_g);
  } else if (b < PREP_W2) {        // W1: R=512, C=2048 -> 32 x 8 x 8 tiles of 64x64
    const int q = b - PREP_W1;
    transpose_tile64(W1, W1t, DIM, FDIM, q & 31, (q >> 5) & 7, q >> 8);
  } else {                         // W2: R=2048, C=512 -> 8 x 32 x 8 tiles of 64x64
    const int q = b - PREP_W2;
    transpose_tile64(W2, W2t, FDIM, DIM, q & 7, (q >> 3) & 31, q >> 8);
  }
}

// ---------------- scan: hist_part -> absolute base_part, offsets, mtile_e ----------------
__global__ __launch_bounds__(256) void scan_kernel(const int* __restrict__ hist_part,
    int* __restrict__ offsets, int* __restrict__ base_part, int* __restrict__ mtile_e) {
  __shared__ int hp[GB_BLOCKS * NEXP];   // 16 KB
  __shared__ int segsum[8][NEXP];
  __shared__ int segbase[8][NEXP];
  __shared__ int tot[NEXP];
  __shared__ int soff[NEXP + 1];
  for (int i = threadIdx.x; i < GB_BLOCKS * NEXP; i += 256) hp[i] = hist_part[i];
  __syncthreads();
  if (threadIdx.x < 64) {
    const int e = threadIdx.x & 7, s = threadIdx.x >> 3;   // 8 segments x 8 experts
    int run = 0;
    for (int b = s * 64; b < s * 64 + 64; b++) {
      int v = hp[b * NEXP + e]; hp[b * NEXP + e] = run; run += v;  // exclusive in-segment
    }
    segsum[s][e] = run;
  }
  __syncthreads();
  if (threadIdx.x < NEXP) {
    const int e = threadIdx.x;
    int run = 0;
    for (int s = 0; s < 8; s++) { segbase[s][e] = run; run += segsum[s][e]; }
    tot[e] = run;
  }
  __syncthreads();
  if (threadIdx.x == 0) {
    int off = 0;
    for (int e = 0; e < NEXP; e++) { soff[e] = off; offsets[e] = off; off += (tot[e] + 127) & ~127; }
    soff[NEXP] = off; offsets[NEXP] = off;
    for (int t = 0; t < NMT; t++) {
      int r = t * 128, e = NEXP - 1;
      for (int q = 0; q < NEXP; q++)
        if (r >= soff[q] && r < soff[q + 1]) { e = q; break; }
      mtile_e[t] = e;
    }
  }
  __syncthreads();
  for (int i = threadIdx.x; i < GB_BLOCKS * NEXP; i += 256) {
    const int b = i >> 3, e = i & 7;
    base_part[i] = soff[e] + segbase[b >> 6][e] + hp[i];
  }
}

// ---------------- gather: resolve rows, write xg (both slots), persist rows ----------------
__global__ void gather_kernel(const float* __restrict__ x, const int2* __restrict__ tok_e,
                              const int2* __restrict__ tok_ls, const int* __restrict__ base_part,
                              ushort4* __restrict__ xg, int2* __restrict__ rows) {
  const int n = blockIdx.x;
  int2 te = tok_e[n]; int2 tl = tok_ls[n];
  const int gb = n / GTPB;
  const int r0 = base_part[gb * NEXP + te.x] + tl.x;
  const int r1 = base_part[gb * NEXP + te.y] + tl.y;
  if (threadIdx.x == 0) rows[n] = make_int2(r0, r1);
  const float4* xr = (const float4*)(x + (size_t)n * DIM);
  float4 v = xr[threadIdx.x];
  ushort4 o;
  o.x = f2bf(v.x); o.y = f2bf(v.y); o.z = f2bf(v.z); o.w = f2bf(v.w);
  xg[(size_t)r0 * (DIM / 4) + threadIdx.x] = o;
  xg[(size_t)r1 * (DIM / 4) + threadIdx.x] = o;
}

// ---------------- 128x128xBK64 bf16 MFMA GEMM core ----------------
// Depth-2 counted-vmcnt pipeline (T3+T4), verified in R3. Double-buffered
// LDS; buffer for K-step t staged at end of step t-2; COUNTED
// s_waitcnt vmcnt(8) (8 newest loads stay in flight across the barrier);
// raw s_barrier; sched_barrier(0) pins ds_read/MFMA ordering (rule #18).
// T5 setprio around MFMA cluster. XOR chunk swizzle: slot [row][c] holds
// global chunk c^(row&7); read side 2-way bank aliasing (free).
template <int K, int LDA, int LDB>
__device__ __forceinline__ void gemm_core(const unsigned short* __restrict__ A,
                                          const unsigned short* __restrict__ B,
                                          int m0, int n0, f32x4 acc[4][4]) {
  __shared__ __align__(16) unsigned short As[2][128 * 64];  // 2 x 16 KB
  __shared__ __align__(16) unsigned short Bs[2][128 * 64];  // 2 x 16 KB
  const int tid = threadIdx.x;
  const int wid = tid >> 6, lane = tid & 63;
  const int wm = (wid >> 1) * 64, wn = (wid & 1) * 64;
  const int quad = lane >> 4, l16 = lane & 15;
  const int srow = tid >> 3;                        // 0..31
  const int scol = ((tid & 7) ^ (srow & 7)) << 3;   // swizzled source chunk (elems)
  const int r7 = (l16 & 7) << 3;                    // read-side swizzle key (elems)
  const unsigned short* Ar = A + (size_t)(m0 + srow) * LDA + scol;
  const unsigned short* Br = B + (size_t)(n0 + srow) * LDB + scol;

  auto stage = [&](int c, int kt) {
    unsigned short* As_w = As[c] + 512 * wid;       // wave-uniform base
    unsigned short* Bs_w = Bs[c] + 512 * wid;
    #pragma unroll
    for (int p = 0; p < 4; p++) {
      gld16(Ar + (size_t)(32 * p) * LDA + kt, As_w + p * 2048);
      gld16(Br + (size_t)(32 * p) * LDB + kt, Bs_w + p * 2048);
    }
  };
  auto compute = [&](int c) {
    __builtin_amdgcn_s_setprio(1);
    #pragma unroll
    for (int kk = 0; kk < 2; kk++) {
      const int swz = ((kk * 4 + quad) << 3) ^ r7;  // swizzled chunk offset (elems)
      bf16x8 af[4], bfr[4];
      #pragma unroll
      for (int i = 0; i < 4; i++) {
        af[i]  = *(const bf16x8*)(As[c] + (wm + i * 16 + l16) * 64 + swz);
        bfr[i] = *(const bf16x8*)(Bs[c] + (wn + i * 16 + l16) * 64 + swz);
      }
      #pragma unroll
      for (int mi = 0; mi < 4; mi++)
        #pragma unroll
        for (int ni = 0; ni < 4; ni++)
          acc[mi][ni] = __builtin_amdgcn_mfma_f32_16x16x32_bf16(af[mi], bfr[ni], acc[mi][ni], 0, 0, 0);
    }
    __builtin_amdgcn_s_setprio(0);
  };

  stage(0, 0);                   // K >= 192 always holds here (K = 512 or 1024)
  stage(1, 64);
  int cur = 0;
  #pragma unroll 1
  for (int kt = 0; kt < K - 128; kt += 64) {
    asm volatile("s_waitcnt vmcnt(8)" ::: "memory");  // oldest 8 (= buf[cur]) landed
    __builtin_amdgcn_s_barrier();                     // all waves: buf[cur] fully written
    __builtin_amdgcn_sched_barrier(0);
    compute(cur);
    __builtin_amdgcn_sched_barrier(0);
    __builtin_amdgcn_s_barrier();                     // all waves done reading buf[cur]
    stage(cur, kt + 128);                             // re-stage 2 steps ahead
    cur ^= 1;
  }
  // penultimate step: 16 outstanding, no further staging
  asm volatile("s_waitcnt vmcnt(8)" ::: "memory");
  __builtin_amdgcn_s_barrier();
  __builtin_amdgcn_sched_barrier(0);
  compute(cur);
  __builtin_amdgcn_sched_barrier(0);
  __builtin_amdgcn_s_barrier();
  cur ^= 1;
  // last step: 8 outstanding -> full drain
  asm volatile("s_waitcnt vmcnt(0)" ::: "memory");
  __builtin_amdgcn_s_barrier();
  __builtin_amdgcn_sched_barrier(0);
  compute(cur);
}

// T1: bijective XCD-chunked swizzle. 8 XCDs; grid multiple of 8. Chunk of
// nwg/8 consecutive swizzled ids lands on one XCD; bn-fast decode keeps a
// chunk's A-panels (~17 x 131KB) inside that XCD's 4MB L2.
__device__ __forceinline__ int xcd_swz(int lin, int chunk) {
  return (lin & 7) * chunk + (lin >> 3);
}

// ---------------- GEMM1: h = relu(xg @ W1[e] + b1[e]) -> bf16 ----------------
// grid: 1-D 2176 = 136 bm x 16 bn, XCD-swizzled, bn-fast within chunk
__global__ __launch_bounds__(256, 2) void gemm1_kernel(const unsigned short* __restrict__ xg,
    const unsigned short* __restrict__ W1t, const int* __restrict__ mtile_e,
    const float* __restrict__ b1, unsigned short* __restrict__ h) {
  const int swz = xcd_swz(blockIdx.x, (NMT * (FDIM / 128)) / 8);  // chunk=272
  const int bm = swz >> 4;          // 0..135
  const int bn = swz & 15;          // 0..15
  const int e = mtile_e[bm];
  f32x4 acc[4][4];
  #pragma unroll
  for (int i = 0; i < 4; i++)
    #pragma unroll
    for (int j = 0; j < 4; j++) acc[i][j] = (f32x4){0.f, 0.f, 0.f, 0.f};
  gemm_core<DIM, DIM, DIM>(xg, W1t + (size_t)e * FDIM * DIM, bm * 128, bn * 128, acc);
  const int tid = threadIdx.x, wid = tid >> 6, lane = tid & 63;
  const int wm = (wid >> 1) * 64, wn = (wid & 1) * 64, quad = lane >> 4, l16 = lane & 15;
  #pragma unroll
  for (int mi = 0; mi < 4; mi++) {
    #pragma unroll
    for (int ni = 0; ni < 4; ni++) {
      const int col = bn * 128 + wn + ni * 16 + l16;
      const float bb = b1[e * FDIM + col];
      #pragma unroll
      for (int r = 0; r < 4; r++) {
        const int row = bm * 128 + wm + mi * 16 + quad * 4 + r;
        float v = acc[mi][ni][r] + bb;
        h[(size_t)row * FDIM + col] = f2bf(v > 0.f ? v : 0.f);
      }
    }
  }
}

// ---------------- GEMM2 (split-K, deterministic): ks=0 -> o0 fp32, ks=1 -> o1 bf16 ----------------
// grid: (544, KSPLIT); 544 = 136 bm x 4 bn, XCD-swizzled per ks-slice
__global__ __launch_bounds__(256, 2) void gemm2_kernel(const unsigned short* __restrict__ h,
    const unsigned short* __restrict__ W2t, const int* __restrict__ mtile_e,
    float* __restrict__ o0, unsigned short* __restrict__ o1) {
  const int swz = xcd_swz(blockIdx.x, (NMT * (DIM / 128)) / 8);   // chunk=68
  const int bm = swz >> 2;          // 0..135
  const int bn = swz & 3;           // 0..3
  const int ks = blockIdx.y;
  const int e = mtile_e[bm];
  const int k0 = ks * (FDIM / KSPLIT);
  f32x4 acc[4][4];
  #pragma unroll
  for (int i = 0; i < 4; i++)
    #pragma unroll
    for (int j = 0; j < 4; j++) acc[i][j] = (f32x4){0.f, 0.f, 0.f, 0.f};
  gemm_core<FDIM / KSPLIT, FDIM, FDIM>(h + k0, W2t + (size_t)e * DIM * FDIM + k0,
                                       bm * 128, bn * 128, acc);
  const int tid = threadIdx.x, wid = tid >> 6, lane = tid & 63;
  const int wm = (wid >> 1) * 64, wn = (wid & 1) * 64, quad = lane >> 4, l16 = lane & 15;
  if (ks == 0) {
    #pragma unroll
    for (int mi = 0; mi < 4; mi++)
      #pragma unroll
      for (int r = 0; r < 4; r++) {
        const int row = bm * 128 + wm + mi * 16 + quad * 4 + r;
        #pragma unroll
        for (int ni = 0; ni < 4; ni++) {
          const int col = bn * 128 + wn + ni * 16 + l16;
          o0[(size_t)row * DIM + col] = acc[mi][ni][r];
        }
      }
  } else {
    #pragma unroll
    for (int mi = 0; mi < 4; mi++)
      #pragma unroll
      for (int r = 0; r < 4; r++) {
        const int row = bm * 128 + wm + mi * 16 + quad * 4 + r;
        #pragma unroll
        for (int ni = 0; ni < 4; ni++) {
          const int col = bn * 128 + wn + ni * 16 + l16;
          o1[(size_t)row * DIM + col] = f2bf(acc[mi][ni][r]);
        }
      }
  }
}

// ---------------- combine: out[n] = log(g0*exp(o(r0)+b2[e0]) + g1*exp(o(r1)+b2[e1])) ----------------
// 256 threads = 2 tokens/block (no wave straddles tokens); native __expf/__logf
// (err ~2 ulp << bf16 partials' rounding floor)
__global__ void combine_kernel(const float* __restrict__ o0, const unsigned short* __restrict__ o1,
                               const int2* __restrict__ tok_e, const int2* __restrict__ rows,
                               const float2* __restrict__ tok_g, const float* __restrict__ b2,
                               float* __restrict__ out) {
  const int n = blockIdx.x * 2 + (threadIdx.x >> 7);
  const int c = (threadIdx.x & 127) * 4;  // 128 threads x float4 per token
  int2 te = tok_e[n]; int2 rr = rows[n]; float2 tg = tok_g[n];
  const int r0 = rr.x, r1 = rr.y;
  float4 a0 = *(const float4*)(o0 + (size_t)r0 * DIM + c);
  float4 a1 = *(const float4*)(o0 + (size_t)r1 * DIM + c);
  ushort4 p0 = *(const ushort4*)(o1 + (size_t)r0 * DIM + c);
  ushort4 p1 = *(const ushort4*)(o1 + (size_t)r1 * DIM + c);
  float4 c0 = *(const float4*)(b2 + te.x * DIM + c);
  float4 c1 = *(const float4*)(b2 + te.y * DIM + c);
  float4 res;
  #pragma unroll
  for (int j = 0; j < 4; j++) {
    float v0 = ((const float*)&a0)[j] + bf2f(((const unsigned short*)&p0)[j]) + ((const float*)&c0)[j];
    float v1 = ((const float*)&a1)[j] + bf2f(((const unsigned short*)&p1)[j]) + ((const float*)&c1)[j];
    float v = tg.x * __expf(v0) + tg.y * __expf(v1);
    v = (v == 0.0f) ? 2.220446049250313e-16f : v;
    ((float*)&res)[j] = __logf(v);
  }
  *(float4*)(out + (size_t)n * DIM + c) = res;
}

extern "C" void kernel_launch(void* const* d_in, const int* in_sizes, int n_in,
                              void* d_out, int out_size, void* d_ws, size_t ws_size,
                              hipStream_t stream) {
  const float* x  = (const float*)d_in[0];
  const float* Wg = (const float*)d_in[1];
  const float* W1 = (const float*)d_in[2];
  const float* b1 = (const float*)d_in[3];
  const float* W2 = (const float*)d_in[4];
  const float* b2 = (const float*)d_in[5];
  float* out = (float*)d_out;
  char* ws = (char*)d_ws;

  unsigned short* W1t = (unsigned short*)(ws + OFF_W1T);
  unsigned short* W2t = (unsigned short*)(ws + OFF_W2T);
  unsigned short* h   = (unsigned short*)(ws + OFF_H);
  int* meta    = (int*)(ws + OFF_META);
  int* offsets = meta;           // [9]
  int* mtile_e = meta + 16;      // [136]
  unsigned short* xg = (unsigned short*)(ws + OFF_XG);
  unsigned short* o1 = (unsigned short*)(ws + OFF_O1);  // aliases xg (dead after gemm1)
  float* o0      = (float*)(ws + OFF_O0);
  int2* tok_e    = (int2*)(ws + OFF_TOKE);
  int2* tok_ls   = (int2*)(ws + OFF_TOKLS);
  float2* tok_g  = (float2*)(ws + OFF_TOKG);
  int* hist_part = (int*)(ws + OFF_HISTP);
  int* base_part = (int*)(ws + OFF_BASEP);
  int2* rows     = (int2*)(ws + OFF_ROWS);

  prep_kernel<<<PREP_TOTAL, 256, 0, stream>>>(W1, W1t, W2, W2t, x, Wg,
                                              hist_part, tok_e, tok_ls, tok_g);
  scan_kernel<<<1, 256, 0, stream>>>(hist_part, offsets, base_part, mtile_e);
  gather_kernel<<<NTOK, 128, 0, stream>>>(x, tok_e, tok_ls, base_part, (ushort4*)xg, rows);
  gemm1_kernel<<<NMT * (FDIM / 128), 256, 0, stream>>>(xg, W1t, mtile_e, b1, h);
  gemm2_kernel<<<dim3(NMT * (DIM / 128), KSPLIT), 256, 0, stream>>>(h, W2t, mtile_e, o0, o1);
  combine_kernel<<<NTOK / 2, 256, 0, stream>>>(o0, o1, tok_e, rows, tok_g, b2, out);
}